// Round 8
// baseline (346.448 us; speedup 1.0000x reference)
//
#include <hip/hip_runtime.h>
#include <hip/hip_bf16.h>
#include <stdint.h>

// B=2, S=4096, D=512, H=8, dk=64. fp32 in/out, bf16 MFMA internals.
// R8: attn = R7's direct-global K/V fragments + barrier-free P-transpose,
// but 32 q/wave -> 2048 one-wave blocks -> 2 waves/SIMD (R7's regression
// was 1 wave/SIMD exposing every dependency stall). XCD-aware bh swizzle
// keeps each XCD's L2 working set to ~2 heads (4 MB).

typedef __bf16 bf16;
typedef __attribute__((ext_vector_type(8))) __bf16 bf16x8;
typedef __attribute__((ext_vector_type(4))) __bf16 bf16x4;
typedef __attribute__((ext_vector_type(4))) float f32x4;

#define LOG2E 1.44269504088896340736f
// Swizzled elem offset of an 8-elem group in a [rows][64] bf16 LDS tile.
#define SW(row, grp) (((row) << 6) + ((((grp) ^ ((row) & 7))) << 3))

// ---------------------------------------------------------------- LayerNorm
__global__ __launch_bounds__(256) void ln_kernel(
    const float* __restrict__ x, const float* __restrict__ gamma,
    const float* __restrict__ beta, bf16* __restrict__ h) {
  int wave = threadIdx.x >> 6, lane = threadIdx.x & 63;
  int row = blockIdx.x * 4 + wave;                 // 8192 rows
  const float* xr = x + (size_t)row * 512 + lane * 8;
  f32x4 v0 = *(const f32x4*)xr;
  f32x4 v1 = *(const f32x4*)(xr + 4);
  float f[8], s = 0.f, s2 = 0.f;
#pragma unroll
  for (int i = 0; i < 4; ++i) { f[i] = v0[i]; f[4 + i] = v1[i]; }
#pragma unroll
  for (int i = 0; i < 8; ++i) { s += f[i]; s2 += f[i] * f[i]; }
#pragma unroll
  for (int off = 1; off < 64; off <<= 1) {
    s  += __shfl_xor(s, off, 64);
    s2 += __shfl_xor(s2, off, 64);
  }
  float mu  = s * (1.f / 512.f);
  float var = s2 * (1.f / 512.f) - mu * mu;
  float rstd = rsqrtf(var + 1e-5f);
  f32x4 g0 = *(const f32x4*)(gamma + lane * 8);
  f32x4 g1 = *(const f32x4*)(gamma + lane * 8 + 4);
  f32x4 b0 = *(const f32x4*)(beta + lane * 8);
  f32x4 b1 = *(const f32x4*)(beta + lane * 8 + 4);
  bf16x8 o;
#pragma unroll
  for (int i = 0; i < 4; ++i) {
    o[i]     = (bf16)((f[i]     - mu) * rstd * g0[i] + b0[i]);
    o[4 + i] = (bf16)((f[4 + i] - mu) * rstd * g1[i] + b1[i]);
  }
  *(bf16x8*)(h + (size_t)row * 512 + lane * 8) = o;
}

// ------------------------------------------------------------- QKV GEMM
__global__ __launch_bounds__(256) void qkv_kernel(
    const bf16* __restrict__ h, const float* __restrict__ wq,
    const float* __restrict__ wk, const float* __restrict__ wv,
    bf16* __restrict__ Qg, bf16* __restrict__ Kg, bf16* __restrict__ Vtg) {
  __shared__ bf16 As[128 * 64];
  __shared__ bf16 Bs[128 * 64];
  int tid = threadIdx.x, wave = tid >> 6, lane = tid & 63;
  int wm = wave >> 1, wn = wave & 1, quad = lane >> 4, l15 = lane & 15;
  int mtile = blockIdx.x;          // 0..63
  int wsel = blockIdx.y >> 2;      // 0=q 1=k 2=v
  int nb = blockIdx.y & 3;
  const float* W = (wsel == 0) ? wq : (wsel == 1 ? wk : wv);
  const bf16*  Abase = h + (size_t)mtile * 128 * 512;
  const float* Bbase = W + (size_t)nb * 128 * 512;
  f32x4 acc[4][4];
#pragma unroll
  for (int i = 0; i < 4; ++i)
#pragma unroll
    for (int j = 0; j < 4; ++j) acc[i][j] = (f32x4){0.f, 0.f, 0.f, 0.f};

  int srow = tid >> 3, grp = tid & 7, scol = grp * 8;
  bf16x8 ar[4];
  f32x4 br0[4], br1[4];
#pragma unroll
  for (int k = 0; k < 4; ++k) {                 // prologue: tile 0 loads
    int rr = srow + k * 32;
    ar[k]  = *(const bf16x8*)(Abase + (size_t)rr * 512 + scol);
    br0[k] = *(const f32x4*)(Bbase + (size_t)rr * 512 + scol);
    br1[k] = *(const f32x4*)(Bbase + (size_t)rr * 512 + scol + 4);
  }
  for (int k0 = 0; k0 < 512; k0 += 64) {
#pragma unroll
    for (int k = 0; k < 4; ++k) {               // regs -> LDS
      int rr = srow + k * 32;
      int w = SW(rr, grp);
      *(bf16x8*)(As + w) = ar[k];
      bf16x8 wb;
#pragma unroll
      for (int j = 0; j < 4; ++j) { wb[j] = (bf16)br0[k][j]; wb[4 + j] = (bf16)br1[k][j]; }
      *(bf16x8*)(Bs + w) = wb;
    }
    __syncthreads();
    if (k0 < 448) {                             // prefetch next tile
#pragma unroll
      for (int k = 0; k < 4; ++k) {
        int rr = srow + k * 32;
        ar[k]  = *(const bf16x8*)(Abase + (size_t)rr * 512 + k0 + 64 + scol);
        br0[k] = *(const f32x4*)(Bbase + (size_t)rr * 512 + k0 + 64 + scol);
        br1[k] = *(const f32x4*)(Bbase + (size_t)rr * 512 + k0 + 64 + scol + 4);
      }
    }
#pragma unroll
    for (int c = 0; c < 2; ++c) {
      bf16x8 af[4], bw[4];
#pragma unroll
      for (int mt = 0; mt < 4; ++mt)
        af[mt] = *(const bf16x8*)(As + SW(wm * 64 + mt * 16 + l15, c * 4 + quad));
#pragma unroll
      for (int nt = 0; nt < 4; ++nt)
        bw[nt] = *(const bf16x8*)(Bs + SW(wn * 64 + nt * 16 + l15, c * 4 + quad));
#pragma unroll
      for (int mt = 0; mt < 4; ++mt)
#pragma unroll
        for (int nt = 0; nt < 4; ++nt)
          acc[mt][nt] = __builtin_amdgcn_mfma_f32_16x16x32_bf16(
              bw[nt], af[mt], acc[mt][nt], 0, 0, 0);
    }
    __syncthreads();
  }
  // Q pre-scale folds softmax 1/sqrt(64) AND log2(e) for exp2-based softmax.
  float qscale = (wsel == 0) ? (0.125f * LOG2E) : 1.0f;
#pragma unroll
  for (int mt = 0; mt < 4; ++mt) {
    int m_g = mtile * 128 + wm * 64 + mt * 16 + l15;   // token
    int b = m_g >> 12, s = m_g & 4095;
#pragma unroll
    for (int nt = 0; nt < 4; ++nt) {
      int n_g = nb * 128 + wn * 64 + nt * 16 + quad * 4;  // feature
      int head = n_g >> 6, d = n_g & 63;
      f32x4 a = acc[mt][nt];
      if (wsel < 2) {
        bf16* dst = (wsel == 0 ? Qg : Kg) +
                    ((size_t)((b * 8 + head) * 4096 + s)) * 64 + d;
        bf16x4 pk;
#pragma unroll
        for (int r = 0; r < 4; ++r) pk[r] = (bf16)(a[r] * qscale);
        *(bf16x4*)dst = pk;
      } else {
        bf16* dst = Vtg + ((size_t)((b * 8 + head) * 64 + d)) * 4096 + s;
#pragma unroll
        for (int r = 0; r < 4; ++r) dst[(size_t)r * 4096] = (bf16)a[r];
      }
    }
  }
}

// --------------------------------------------------------- Flash attention
// One wave per block, 32 q-rows. K/V fragments straight from global (L2).
__device__ __forceinline__ void attn_tile(
    const bf16* __restrict__ Kh, const bf16* __restrict__ Vth,
    int ktn, bool pf,
    bf16x8 (&kfc)[8], bf16x8 (&vfc)[8],
    bf16x8 (&kfn)[8], bf16x8 (&vfn)[8],
    const bf16x8 (&qf)[2][2], f32x4 (&o_acc)[2][4], float (&l_part)[2],
    bf16* __restrict__ Ps, int quad, int l15) {
  // ---- prefetch next tile's K/V fragments (global, 16B/lane, L2-hot)
  if (pf) {
#pragma unroll
    for (int kb = 0; kb < 4; ++kb)
#pragma unroll
      for (int c = 0; c < 2; ++c)
        kfn[kb * 2 + c] = *(const bf16x8*)(
            Kh + (size_t)(ktn * 64 + kb * 16 + l15) * 64 + c * 32 + quad * 8);
#pragma unroll
    for (int nt = 0; nt < 4; ++nt)
#pragma unroll
      for (int c = 0; c < 2; ++c)
        vfn[nt * 2 + c] = *(const bf16x8*)(
            Vth + (size_t)(nt * 16 + l15) * 4096 + ktn * 64 + c * 32 + quad * 8);
  }
  // ---- QK^T transposed per mt: S^T[key=kb*16+quad*4+r][q=l15]
#pragma unroll
  for (int mt = 0; mt < 2; ++mt) {
    f32x4 st[4];
#pragma unroll
    for (int kb = 0; kb < 4; ++kb) st[kb] = (f32x4){0.f, 0.f, 0.f, 0.f};
#pragma unroll
    for (int c = 0; c < 2; ++c)
#pragma unroll
      for (int kb = 0; kb < 4; ++kb)
        st[kb] = __builtin_amdgcn_mfma_f32_16x16x32_bf16(
            kfc[kb * 2 + c], qf[mt][c], st[kb], 0, 0, 0);
#pragma unroll
    for (int kb = 0; kb < 4; ++kb) {
      bf16x4 pk;
#pragma unroll
      for (int r = 0; r < 4; ++r) {
        float pv = __builtin_amdgcn_exp2f(st[kb][r]);
        l_part[mt] += pv;
        pk[r] = (bf16)pv;
      }
      *(bf16x4*)(&Ps[mt * 1024 +
                     SW(l15, kb * 2 + (quad >> 1)) + (quad & 1) * 4]) = pk;
    }
  }
  asm volatile("s_waitcnt lgkmcnt(0)" ::: "memory");  // wave-local P fence
  // ---- PV: O[q][d=nt*16+l15]
#pragma unroll
  for (int c = 0; c < 2; ++c) {
    bf16x8 pfr[2];
#pragma unroll
    for (int mt = 0; mt < 2; ++mt)
      pfr[mt] = *(const bf16x8*)(&Ps[mt * 1024 + SW(l15, c * 4 + quad)]);
#pragma unroll
    for (int nt = 0; nt < 4; ++nt)
#pragma unroll
      for (int mt = 0; mt < 2; ++mt)
        o_acc[mt][nt] = __builtin_amdgcn_mfma_f32_16x16x32_bf16(
            pfr[mt], vfc[nt * 2 + c], o_acc[mt][nt], 0, 0, 0);
  }
}

__global__ __launch_bounds__(64, 2) void attn_kernel(
    const bf16* __restrict__ Qg, const bf16* __restrict__ Kg,
    const bf16* __restrict__ Vtg, bf16* __restrict__ Og) {
  __shared__ bf16 Ps[2 * 16 * 64];      // 4 KB: per-mt P strips [16q][64key]
  int lane = threadIdx.x;
  int quad = lane >> 4, l15 = lane & 15;
  // XCD-aware decode: consecutive block IDs round-robin XCDs; give each XCD
  // a ~2-head working set (4 MB K+V in its L2).
  int bid = blockIdx.x;                 // 0..2047
  int idx = bid >> 3;                   // 0..255
  int bh  = ((bid & 7) << 1) | (idx & 1);
  int q0  = (idx >> 1) * 32;
  int hi = bh & 7, bi = bh >> 3;
  const bf16* Kh  = Kg  + (size_t)bh * 4096 * 64;
  const bf16* Vth = Vtg + (size_t)bh * 64 * 4096;

  bf16x8 qf[2][2];   // Q pre-scaled by 0.125*LOG2E in qkv
#pragma unroll
  for (int mt = 0; mt < 2; ++mt)
#pragma unroll
    for (int c = 0; c < 2; ++c)
      qf[mt][c] = *(const bf16x8*)(
          Qg + ((size_t)bh * 4096 + q0 + mt * 16 + l15) * 64 + c * 32 + quad * 8);

  f32x4 o_acc[2][4];
  float l_part[2] = {0.f, 0.f};
#pragma unroll
  for (int mt = 0; mt < 2; ++mt)
#pragma unroll
    for (int nt = 0; nt < 4; ++nt) o_acc[mt][nt] = (f32x4){0.f, 0.f, 0.f, 0.f};

  bf16x8 kfA[8], vfA[8], kfB[8], vfB[8];
  // prologue: tile 0 fragments
#pragma unroll
  for (int kb = 0; kb < 4; ++kb)
#pragma unroll
    for (int c = 0; c < 2; ++c)
      kfA[kb * 2 + c] = *(const bf16x8*)(
          Kh + (size_t)(kb * 16 + l15) * 64 + c * 32 + quad * 8);
#pragma unroll
  for (int nt = 0; nt < 4; ++nt)
#pragma unroll
    for (int c = 0; c < 2; ++c)
      vfA[nt * 2 + c] = *(const bf16x8*)(
          Vth + (size_t)(nt * 16 + l15) * 4096 + c * 32 + quad * 8);

  for (int kt = 0; kt < 64; kt += 2) {
    attn_tile(Kh, Vth, kt + 1, true,
              kfA, vfA, kfB, vfB, qf, o_acc, l_part, Ps, quad, l15);
    attn_tile(Kh, Vth, kt + 2, (kt + 2) < 64,
              kfB, vfB, kfA, vfA, qf, o_acc, l_part, Ps, quad, l15);
  }
  // ---- l: reduce across quads (lanes same l15), then row-indexed fetch
#pragma unroll
  for (int mt = 0; mt < 2; ++mt) {
    l_part[mt] += __shfl_xor(l_part[mt], 16, 64);
    l_part[mt] += __shfl_xor(l_part[mt], 32, 64);
  }
#pragma unroll
  for (int mt = 0; mt < 2; ++mt)
#pragma unroll
    for (int r = 0; r < 4; ++r) {
      float lr = __shfl(l_part[mt], quad * 4 + r, 64);  // lane l15==q holds l
      float inv = 1.0f / lr;
      int q = q0 + mt * 16 + quad * 4 + r;
      size_t row = ((size_t)bi * 4096 + q) * 512 + hi * 64;
#pragma unroll
      for (int nt = 0; nt < 4; ++nt)
        Og[row + nt * 16 + l15] = (bf16)(o_acc[mt][nt][r] * inv);
    }
}

// ----------------------------------------------- out = A @ Wo^T + bo + x
__global__ __launch_bounds__(256) void proj_kernel(
    const bf16* __restrict__ A, const float* __restrict__ Wo,
    const float* __restrict__ bo, const float* __restrict__ x,
    float* __restrict__ out) {
  __shared__ bf16 As[128 * 64];
  __shared__ bf16 Bs[128 * 64];
  int tid = threadIdx.x, wave = tid >> 6, lane = tid & 63;
  int wm = wave >> 1, wn = wave & 1, quad = lane >> 4, l15 = lane & 15;
  int mtile = blockIdx.x, nb = blockIdx.y;
  const bf16*  Abase = A + (size_t)mtile * 128 * 512;
  const float* Bbase = Wo + (size_t)nb * 128 * 512;
  f32x4 acc[4][4];
#pragma unroll
  for (int i = 0; i < 4; ++i)
#pragma unroll
    for (int j = 0; j < 4; ++j) acc[i][j] = (f32x4){0.f, 0.f, 0.f, 0.f};

  int srow = tid >> 3, grp = tid & 7, scol = grp * 8;
  bf16x8 ar[4];
  f32x4 br0[4], br1[4];
#pragma unroll
  for (int k = 0; k < 4; ++k) {
    int rr = srow + k * 32;
    ar[k]  = *(const bf16x8*)(Abase + (size_t)rr * 512 + scol);
    br0[k] = *(const f32x4*)(Bbase + (size_t)rr * 512 + scol);
    br1[k] = *(const f32x4*)(Bbase + (size_t)rr * 512 + scol + 4);
  }
  for (int k0 = 0; k0 < 512; k0 += 64) {
#pragma unroll
    for (int k = 0; k < 4; ++k) {
      int rr = srow + k * 32;
      int w = SW(rr, grp);
      *(bf16x8*)(As + w) = ar[k];
      bf16x8 wb;
#pragma unroll
      for (int j = 0; j < 4; ++j) { wb[j] = (bf16)br0[k][j]; wb[4 + j] = (bf16)br1[k][j]; }
      *(bf16x8*)(Bs + w) = wb;
    }
    __syncthreads();
    if (k0 < 448) {
#pragma unroll
      for (int k = 0; k < 4; ++k) {
        int rr = srow + k * 32;
        ar[k]  = *(const bf16x8*)(Abase + (size_t)rr * 512 + k0 + 64 + scol);
        br0[k] = *(const f32x4*)(Bbase + (size_t)rr * 512 + k0 + 64 + scol);
        br1[k] = *(const f32x4*)(Bbase + (size_t)rr * 512 + k0 + 64 + scol + 4);
      }
    }
#pragma unroll
    for (int c = 0; c < 2; ++c) {
      bf16x8 af[4], bw[4];
#pragma unroll
      for (int mt = 0; mt < 4; ++mt)
        af[mt] = *(const bf16x8*)(As + SW(wm * 64 + mt * 16 + l15, c * 4 + quad));
#pragma unroll
      for (int nt = 0; nt < 4; ++nt)
        bw[nt] = *(const bf16x8*)(Bs + SW(wn * 64 + nt * 16 + l15, c * 4 + quad));
#pragma unroll
      for (int mt = 0; mt < 4; ++mt)
#pragma unroll
        for (int nt = 0; nt < 4; ++nt)
          acc[mt][nt] = __builtin_amdgcn_mfma_f32_16x16x32_bf16(
              bw[nt], af[mt], acc[mt][nt], 0, 0, 0);
    }
    __syncthreads();
  }
#pragma unroll
  for (int mt = 0; mt < 4; ++mt) {
    int m_g = mtile * 128 + wm * 64 + mt * 16 + l15;
#pragma unroll
    for (int nt = 0; nt < 4; ++nt) {
      int n_g = nb * 128 + wn * 64 + nt * 16 + quad * 4;
      f32x4 a = acc[mt][nt];
      f32x4 xr = *(const f32x4*)(x + (size_t)m_g * 512 + n_g);
      f32x4 bb = *(const f32x4*)(bo + n_g);
      f32x4 o;
#pragma unroll
      for (int r = 0; r < 4; ++r)
        o[r] = a[r] + bb[r] + xr[r];
      *(f32x4*)(out + (size_t)m_g * 512 + n_g) = o;
    }
  }
}

extern "C" void kernel_launch(void* const* d_in, const int* in_sizes, int n_in,
                              void* d_out, int out_size, void* d_ws, size_t ws_size,
                              hipStream_t stream) {
  const float* x     = (const float*)d_in[0];
  const float* wq    = (const float*)d_in[1];
  const float* wk    = (const float*)d_in[2];
  const float* wv    = (const float*)d_in[3];
  const float* wo    = (const float*)d_in[4];
  const float* bo    = (const float*)d_in[5];
  const float* gamma = (const float*)d_in[6];
  const float* beta  = (const float*)d_in[7];
  float* out = (float*)d_out;
  char* ws = (char*)d_ws;
  const size_t SZ = (size_t)8192 * 512 * sizeof(bf16);  // 8 MB
  bf16* h   = (bf16*)(ws);          // aliased with Ao (h dead before attn)
  bf16* Ao  = (bf16*)(ws);
  bf16* Qg  = (bf16*)(ws + SZ);
  bf16* Kg  = (bf16*)(ws + 2 * SZ);
  bf16* Vtg = (bf16*)(ws + 3 * SZ);

  ln_kernel<<<2048, 256, 0, stream>>>(x, gamma, beta, h);
  qkv_kernel<<<dim3(64, 12), 256, 0, stream>>>(h, wq, wk, wv, Qg, Kg, Vtg);
  attn_kernel<<<2048, 64, 0, stream>>>(Qg, Kg, Vtg, Ao);
  proj_kernel<<<dim3(64, 4), 256, 0, stream>>>(Ao, wo, bo, x, out);
}

// Round 9
// 226.230 us; speedup vs baseline: 1.5314x; 1.5314x over previous
//
#include <hip/hip_runtime.h>
#include <hip/hip_bf16.h>
#include <stdint.h>

// B=2, S=4096, D=512, H=8, dk=64. fp32 in/out, bf16 MFMA internals.
// R9: attn = R6 LDS-staged structure (global loads MUST be wave-contiguous;
// R7/R8 proved divergent fragment loads shatter in TA at ~64cyc/instr), but:
//  - 64 q/wave (mt=4): halves the dominant K/V LDS fragment-read cost per q
//  - 2-way key split keeps 2048 waves (8/CU); no-max softmax makes the
//    merge pure addition of (O, l) partials via LDS epilogue
//  - block = 4 waves (2 qgrp x 2 khalf), single-buffered 32KB staging with
//    register prefetch, per-wave P strip, 4 sequential mt-rounds (40KB LDS)

typedef __bf16 bf16;
typedef __attribute__((ext_vector_type(8))) __bf16 bf16x8;
typedef __attribute__((ext_vector_type(4))) __bf16 bf16x4;
typedef __attribute__((ext_vector_type(4))) float f32x4;

#define LOG2E 1.44269504088896340736f
// Swizzled elem offset of an 8-elem group in a [rows][64] bf16 LDS tile.
#define SW(row, grp) (((row) << 6) + ((((grp) ^ ((row) & 7))) << 3))

// ---------------------------------------------------------------- LayerNorm
__global__ __launch_bounds__(256) void ln_kernel(
    const float* __restrict__ x, const float* __restrict__ gamma,
    const float* __restrict__ beta, bf16* __restrict__ h) {
  int wave = threadIdx.x >> 6, lane = threadIdx.x & 63;
  int row = blockIdx.x * 4 + wave;                 // 8192 rows
  const float* xr = x + (size_t)row * 512 + lane * 8;
  f32x4 v0 = *(const f32x4*)xr;
  f32x4 v1 = *(const f32x4*)(xr + 4);
  float f[8], s = 0.f, s2 = 0.f;
#pragma unroll
  for (int i = 0; i < 4; ++i) { f[i] = v0[i]; f[4 + i] = v1[i]; }
#pragma unroll
  for (int i = 0; i < 8; ++i) { s += f[i]; s2 += f[i] * f[i]; }
#pragma unroll
  for (int off = 1; off < 64; off <<= 1) {
    s  += __shfl_xor(s, off, 64);
    s2 += __shfl_xor(s2, off, 64);
  }
  float mu  = s * (1.f / 512.f);
  float var = s2 * (1.f / 512.f) - mu * mu;
  float rstd = rsqrtf(var + 1e-5f);
  f32x4 g0 = *(const f32x4*)(gamma + lane * 8);
  f32x4 g1 = *(const f32x4*)(gamma + lane * 8 + 4);
  f32x4 b0 = *(const f32x4*)(beta + lane * 8);
  f32x4 b1 = *(const f32x4*)(beta + lane * 8 + 4);
  bf16x8 o;
#pragma unroll
  for (int i = 0; i < 4; ++i) {
    o[i]     = (bf16)((f[i]     - mu) * rstd * g0[i] + b0[i]);
    o[4 + i] = (bf16)((f[4 + i] - mu) * rstd * g1[i] + b1[i]);
  }
  *(bf16x8*)(h + (size_t)row * 512 + lane * 8) = o;
}

// ------------------------------------------------------------- QKV GEMM
__global__ __launch_bounds__(256) void qkv_kernel(
    const bf16* __restrict__ h, const float* __restrict__ wq,
    const float* __restrict__ wk, const float* __restrict__ wv,
    bf16* __restrict__ Qg, bf16* __restrict__ Kg, bf16* __restrict__ Vtg) {
  __shared__ bf16 As[128 * 64];
  __shared__ bf16 Bs[128 * 64];
  int tid = threadIdx.x, wave = tid >> 6, lane = tid & 63;
  int wm = wave >> 1, wn = wave & 1, quad = lane >> 4, l15 = lane & 15;
  int mtile = blockIdx.x;          // 0..63
  int wsel = blockIdx.y >> 2;      // 0=q 1=k 2=v
  int nb = blockIdx.y & 3;
  const float* W = (wsel == 0) ? wq : (wsel == 1 ? wk : wv);
  const bf16*  Abase = h + (size_t)mtile * 128 * 512;
  const float* Bbase = W + (size_t)nb * 128 * 512;
  f32x4 acc[4][4];
#pragma unroll
  for (int i = 0; i < 4; ++i)
#pragma unroll
    for (int j = 0; j < 4; ++j) acc[i][j] = (f32x4){0.f, 0.f, 0.f, 0.f};

  int srow = tid >> 3, grp = tid & 7, scol = grp * 8;
  bf16x8 ar[4];
  f32x4 br0[4], br1[4];
#pragma unroll
  for (int k = 0; k < 4; ++k) {                 // prologue: tile 0 loads
    int rr = srow + k * 32;
    ar[k]  = *(const bf16x8*)(Abase + (size_t)rr * 512 + scol);
    br0[k] = *(const f32x4*)(Bbase + (size_t)rr * 512 + scol);
    br1[k] = *(const f32x4*)(Bbase + (size_t)rr * 512 + scol + 4);
  }
  for (int k0 = 0; k0 < 512; k0 += 64) {
#pragma unroll
    for (int k = 0; k < 4; ++k) {               // regs -> LDS
      int rr = srow + k * 32;
      int w = SW(rr, grp);
      *(bf16x8*)(As + w) = ar[k];
      bf16x8 wb;
#pragma unroll
      for (int j = 0; j < 4; ++j) { wb[j] = (bf16)br0[k][j]; wb[4 + j] = (bf16)br1[k][j]; }
      *(bf16x8*)(Bs + w) = wb;
    }
    __syncthreads();
    if (k0 < 448) {                             // prefetch next tile
#pragma unroll
      for (int k = 0; k < 4; ++k) {
        int rr = srow + k * 32;
        ar[k]  = *(const bf16x8*)(Abase + (size_t)rr * 512 + k0 + 64 + scol);
        br0[k] = *(const f32x4*)(Bbase + (size_t)rr * 512 + k0 + 64 + scol);
        br1[k] = *(const f32x4*)(Bbase + (size_t)rr * 512 + k0 + 64 + scol + 4);
      }
    }
#pragma unroll
    for (int c = 0; c < 2; ++c) {
      bf16x8 af[4], bw[4];
#pragma unroll
      for (int mt = 0; mt < 4; ++mt)
        af[mt] = *(const bf16x8*)(As + SW(wm * 64 + mt * 16 + l15, c * 4 + quad));
#pragma unroll
      for (int nt = 0; nt < 4; ++nt)
        bw[nt] = *(const bf16x8*)(Bs + SW(wn * 64 + nt * 16 + l15, c * 4 + quad));
#pragma unroll
      for (int mt = 0; mt < 4; ++mt)
#pragma unroll
        for (int nt = 0; nt < 4; ++nt)
          acc[mt][nt] = __builtin_amdgcn_mfma_f32_16x16x32_bf16(
              bw[nt], af[mt], acc[mt][nt], 0, 0, 0);
    }
    __syncthreads();
  }
  // Q pre-scale folds softmax 1/sqrt(64) AND log2(e) for exp2-based softmax.
  float qscale = (wsel == 0) ? (0.125f * LOG2E) : 1.0f;
#pragma unroll
  for (int mt = 0; mt < 4; ++mt) {
    int m_g = mtile * 128 + wm * 64 + mt * 16 + l15;   // token
    int b = m_g >> 12, s = m_g & 4095;
#pragma unroll
    for (int nt = 0; nt < 4; ++nt) {
      int n_g = nb * 128 + wn * 64 + nt * 16 + quad * 4;  // feature
      int head = n_g >> 6, d = n_g & 63;
      f32x4 a = acc[mt][nt];
      if (wsel < 2) {
        bf16* dst = (wsel == 0 ? Qg : Kg) +
                    ((size_t)((b * 8 + head) * 4096 + s)) * 64 + d;
        bf16x4 pk;
#pragma unroll
        for (int r = 0; r < 4; ++r) pk[r] = (bf16)(a[r] * qscale);
        *(bf16x4*)dst = pk;
      } else {
        bf16* dst = Vtg + ((size_t)((b * 8 + head) * 64 + d)) * 4096 + s;
#pragma unroll
        for (int r = 0; r < 4; ++r) dst[(size_t)r * 4096] = (bf16)a[r];
      }
    }
  }
}

// --------------------------------------------------------- Flash attention
// Block: 256 thr = 4 waves = (qgrp 0/1) x (khalf 0/1). 64 q/wave, keys
// [khalf*2048, +2048) in 32 tiles of 64. Merge partials via LDS (pure add).
__global__ __launch_bounds__(256, 2) void attn_kernel(
    const bf16* __restrict__ Qg, const bf16* __restrict__ Kg,
    const bf16* __restrict__ Vtg, bf16* __restrict__ Og) {
  __shared__ char smem[40 * 1024];
  bf16* KV = (bf16*)smem;               // [half][K 4096 | V 4096] elems
  bf16* Ps = KV + 16384;                // 4 strips x 1024 elems (8 KB)
  float* OL = (float*)smem;             // merge reuse: 2 x 4096 f32 (32 KB)
  float* Ll = (float*)(smem + 32768);   // merge l: 128 f32 (in strip area)

  int tid = threadIdx.x, wave = tid >> 6, lane = tid & 63;
  int quad = lane >> 4, l15 = lane & 15;
  int qgrp = wave & 1, khalf = wave >> 1;
  int q0 = blockIdx.x * 128;
  int bh = blockIdx.y;
  int hi = bh & 7, bi = bh >> 3;
  const bf16* Kh  = Kg  + (size_t)bh * 4096 * 64;
  const bf16* Vth = Vtg + (size_t)bh * 64 * 4096;

  bf16x8 qf[4][2];   // Q pre-scaled by 0.125*LOG2E in qkv
#pragma unroll
  for (int mt = 0; mt < 4; ++mt)
#pragma unroll
    for (int c = 0; c < 2; ++c)
      qf[mt][c] = *(const bf16x8*)(
          Qg + ((size_t)bh * 4096 + q0 + qgrp * 64 + mt * 16 + l15) * 64 +
          c * 32 + quad * 8);

  f32x4 o_acc[4][4];
  float l_part[4] = {0.f, 0.f, 0.f, 0.f};
#pragma unroll
  for (int mt = 0; mt < 4; ++mt)
#pragma unroll
    for (int nt = 0; nt < 4; ++nt) o_acc[mt][nt] = (f32x4){0.f, 0.f, 0.f, 0.f};

  // Staging: wave w stages stream half (w>>1); K if (w&1)==0 else V.
  // 8 KB/wave = 8 contiguous bf16x8 chunks/lane.
  bf16* stage_dst = KV + khalf * 8192 + ((wave & 1) ? 4096 : 0);
  bool stage_v = (wave & 1) != 0;
  bf16x8 sr[8];
  int key0 = khalf * 2048;
#pragma unroll
  for (int i = 0; i < 8; ++i) {          // prologue: tile 0
    int e = i * 512 + lane * 8;
    sr[i] = stage_v
        ? *(const bf16x8*)(Vth + (size_t)(e >> 6) * 4096 + key0 + (e & 63))
        : *(const bf16x8*)(Kh + (size_t)(key0) * 64 + e);
  }
  bf16* Ksw = KV + khalf * 8192;
  bf16* Vsw = Ksw + 4096;
  bf16* Pw  = Ps + wave * 1024;

  for (int kt = 0; kt < 32; ++kt) {
    __syncthreads();                     // prev tile's LDS reads done
#pragma unroll
    for (int i = 0; i < 8; ++i) {        // regs -> LDS (swizzled)
      int e = i * 512 + lane * 8;
      *(bf16x8*)(stage_dst + SW(e >> 6, (e >> 3) & 7)) = sr[i];
    }
    __syncthreads();                     // staging visible
    if (kt < 31) {
      int kbase = key0 + (kt + 1) * 64;
#pragma unroll
      for (int i = 0; i < 8; ++i) {
        int e = i * 512 + lane * 8;
        sr[i] = stage_v
            ? *(const bf16x8*)(Vth + (size_t)(e >> 6) * 4096 + kbase + (e & 63))
            : *(const bf16x8*)(Kh + (size_t)kbase * 64 + e);
      }
    }
    // fragment reads (this wave's key-half)
    bf16x8 kf[8], vf[8];
#pragma unroll
    for (int kb = 0; kb < 4; ++kb)
#pragma unroll
      for (int c = 0; c < 2; ++c) {
        kf[kb * 2 + c] = *(const bf16x8*)(Ksw + SW(kb * 16 + l15, c * 4 + quad));
        vf[kb * 2 + c] = *(const bf16x8*)(Vsw + SW(kb * 16 + l15, c * 4 + quad));
      }
    // 4 sequential mt rounds
#pragma unroll
    for (int mt = 0; mt < 4; ++mt) {
      f32x4 st[4];
#pragma unroll
      for (int kb = 0; kb < 4; ++kb) st[kb] = (f32x4){0.f, 0.f, 0.f, 0.f};
#pragma unroll
      for (int c = 0; c < 2; ++c)
#pragma unroll
        for (int kb = 0; kb < 4; ++kb)
          st[kb] = __builtin_amdgcn_mfma_f32_16x16x32_bf16(
              kf[kb * 2 + c], qf[mt][c], st[kb], 0, 0, 0);
#pragma unroll
      for (int kb = 0; kb < 4; ++kb) {
        bf16x4 pk;
#pragma unroll
        for (int r = 0; r < 4; ++r) {
          float pv = __builtin_amdgcn_exp2f(st[kb][r]);
          l_part[mt] += pv;
          pk[r] = (bf16)pv;
        }
        *(bf16x4*)(&Pw[SW(l15, kb * 2 + (quad >> 1)) + (quad & 1) * 4]) = pk;
      }
      __builtin_amdgcn_s_waitcnt(0xC07F);   // lgkmcnt(0): P strip visible
#pragma unroll
      for (int c = 0; c < 2; ++c) {
        bf16x8 pf = *(const bf16x8*)(&Pw[SW(l15, c * 4 + quad)]);
#pragma unroll
        for (int nt = 0; nt < 4; ++nt)
          o_acc[mt][nt] = __builtin_amdgcn_mfma_f32_16x16x32_bf16(
              pf, vf[nt * 2 + c], o_acc[mt][nt], 0, 0, 0);
      }
    }
  }
  // ---- merge the two key-halves (pure addition; no-max softmax) ----
  __syncthreads();                        // all LDS tile use done
#pragma unroll
  for (int mt = 0; mt < 4; ++mt) {        // l: reduce quads -> lane l15 = q
    l_part[mt] += __shfl_xor(l_part[mt], 16, 64);
    l_part[mt] += __shfl_xor(l_part[mt], 32, 64);
  }
  if (khalf == 1) {
    float* dst = OL + qgrp * 4096;
#pragma unroll
    for (int mt = 0; mt < 4; ++mt) {
#pragma unroll
      for (int nt = 0; nt < 4; ++nt)
#pragma unroll
        for (int r = 0; r < 4; ++r)
          dst[(mt * 16 + quad * 4 + r) * 64 + nt * 16 + l15] = o_acc[mt][nt][r];
      if (quad == 0) Ll[qgrp * 64 + mt * 16 + l15] = l_part[mt];
    }
  }
  __syncthreads();
  if (khalf == 0) {
    const float* src = OL + qgrp * 4096;
#pragma unroll
    for (int mt = 0; mt < 4; ++mt) {
#pragma unroll
      for (int nt = 0; nt < 4; ++nt)
#pragma unroll
        for (int r = 0; r < 4; ++r)
          o_acc[mt][nt][r] += src[(mt * 16 + quad * 4 + r) * 64 + nt * 16 + l15];
      l_part[mt] += Ll[qgrp * 64 + mt * 16 + l15];
    }
#pragma unroll
    for (int mt = 0; mt < 4; ++mt)
#pragma unroll
      for (int r = 0; r < 4; ++r) {
        float lr = __shfl(l_part[mt], quad * 4 + r, 64);
        float inv = 1.0f / lr;
        int q = q0 + qgrp * 64 + mt * 16 + quad * 4 + r;
        size_t row = ((size_t)bi * 4096 + q) * 512 + hi * 64;
#pragma unroll
        for (int nt = 0; nt < 4; ++nt)
          Og[row + nt * 16 + l15] = (bf16)(o_acc[mt][nt][r] * inv);
      }
  }
}

// ----------------------------------------------- out = A @ Wo^T + bo + x
__global__ __launch_bounds__(256) void proj_kernel(
    const bf16* __restrict__ A, const float* __restrict__ Wo,
    const float* __restrict__ bo, const float* __restrict__ x,
    float* __restrict__ out) {
  __shared__ bf16 As[128 * 64];
  __shared__ bf16 Bs[128 * 64];
  int tid = threadIdx.x, wave = tid >> 6, lane = tid & 63;
  int wm = wave >> 1, wn = wave & 1, quad = lane >> 4, l15 = lane & 15;
  int mtile = blockIdx.x, nb = blockIdx.y;
  const bf16*  Abase = A + (size_t)mtile * 128 * 512;
  const float* Bbase = Wo + (size_t)nb * 128 * 512;
  f32x4 acc[4][4];
#pragma unroll
  for (int i = 0; i < 4; ++i)
#pragma unroll
    for (int j = 0; j < 4; ++j) acc[i][j] = (f32x4){0.f, 0.f, 0.f, 0.f};

  int srow = tid >> 3, grp = tid & 7, scol = grp * 8;
  bf16x8 ar[4];
  f32x4 br0[4], br1[4];
#pragma unroll
  for (int k = 0; k < 4; ++k) {
    int rr = srow + k * 32;
    ar[k]  = *(const bf16x8*)(Abase + (size_t)rr * 512 + scol);
    br0[k] = *(const f32x4*)(Bbase + (size_t)rr * 512 + scol);
    br1[k] = *(const f32x4*)(Bbase + (size_t)rr * 512 + scol + 4);
  }
  for (int k0 = 0; k0 < 512; k0 += 64) {
#pragma unroll
    for (int k = 0; k < 4; ++k) {
      int rr = srow + k * 32;
      int w = SW(rr, grp);
      *(bf16x8*)(As + w) = ar[k];
      bf16x8 wb;
#pragma unroll
      for (int j = 0; j < 4; ++j) { wb[j] = (bf16)br0[k][j]; wb[4 + j] = (bf16)br1[k][j]; }
      *(bf16x8*)(Bs + w) = wb;
    }
    __syncthreads();
    if (k0 < 448) {
#pragma unroll
      for (int k = 0; k < 4; ++k) {
        int rr = srow + k * 32;
        ar[k]  = *(const bf16x8*)(Abase + (size_t)rr * 512 + k0 + 64 + scol);
        br0[k] = *(const f32x4*)(Bbase + (size_t)rr * 512 + k0 + 64 + scol);
        br1[k] = *(const f32x4*)(Bbase + (size_t)rr * 512 + k0 + 64 + scol + 4);
      }
    }
#pragma unroll
    for (int c = 0; c < 2; ++c) {
      bf16x8 af[4], bw[4];
#pragma unroll
      for (int mt = 0; mt < 4; ++mt)
        af[mt] = *(const bf16x8*)(As + SW(wm * 64 + mt * 16 + l15, c * 4 + quad));
#pragma unroll
      for (int nt = 0; nt < 4; ++nt)
        bw[nt] = *(const bf16x8*)(Bs + SW(wn * 64 + nt * 16 + l15, c * 4 + quad));
#pragma unroll
      for (int mt = 0; mt < 4; ++mt)
#pragma unroll
        for (int nt = 0; nt < 4; ++nt)
          acc[mt][nt] = __builtin_amdgcn_mfma_f32_16x16x32_bf16(
              bw[nt], af[mt], acc[mt][nt], 0, 0, 0);
    }
    __syncthreads();
  }
#pragma unroll
  for (int mt = 0; mt < 4; ++mt) {
    int m_g = mtile * 128 + wm * 64 + mt * 16 + l15;
#pragma unroll
    for (int nt = 0; nt < 4; ++nt) {
      int n_g = nb * 128 + wn * 64 + nt * 16 + quad * 4;
      f32x4 a = acc[mt][nt];
      f32x4 xr = *(const f32x4*)(x + (size_t)m_g * 512 + n_g);
      f32x4 bb = *(const f32x4*)(bo + n_g);
      f32x4 o;
#pragma unroll
      for (int r = 0; r < 4; ++r)
        o[r] = a[r] + bb[r] + xr[r];
      *(f32x4*)(out + (size_t)m_g * 512 + n_g) = o;
    }
  }
}

extern "C" void kernel_launch(void* const* d_in, const int* in_sizes, int n_in,
                              void* d_out, int out_size, void* d_ws, size_t ws_size,
                              hipStream_t stream) {
  const float* x     = (const float*)d_in[0];
  const float* wq    = (const float*)d_in[1];
  const float* wk    = (const float*)d_in[2];
  const float* wv    = (const float*)d_in[3];
  const float* wo    = (const float*)d_in[4];
  const float* bo    = (const float*)d_in[5];
  const float* gamma = (const float*)d_in[6];
  const float* beta  = (const float*)d_in[7];
  float* out = (float*)d_out;
  char* ws = (char*)d_ws;
  const size_t SZ = (size_t)8192 * 512 * sizeof(bf16);  // 8 MB
  bf16* h   = (bf16*)(ws);          // aliased with Ao (h dead before attn)
  bf16* Ao  = (bf16*)(ws);
  bf16* Qg  = (bf16*)(ws + SZ);
  bf16* Kg  = (bf16*)(ws + 2 * SZ);
  bf16* Vtg = (bf16*)(ws + 3 * SZ);

  ln_kernel<<<2048, 256, 0, stream>>>(x, gamma, beta, h);
  qkv_kernel<<<dim3(64, 12), 256, 0, stream>>>(h, wq, wk, wv, Qg, Kg, Vtg);
  attn_kernel<<<dim3(32, 16), 256, 0, stream>>>(Qg, Kg, Vtg, Ao);
  proj_kernel<<<dim3(64, 4), 256, 0, stream>>>(Ao, wo, bo, x, out);
}

// Round 10
// 210.017 us; speedup vs baseline: 1.6496x; 1.0772x over previous
//
#include <hip/hip_runtime.h>
#include <hip/hip_bf16.h>
#include <stdint.h>

// B=2, S=4096, D=512, H=8, dk=64. fp32 in/out, bf16 MFMA internals.
// R10: attn — kill the P LDS round-trip: S^T D-layout (lane holds
// P[q=l15][key=quad*4+r]) IS the K=16 MFMA B-operand layout, so PV runs as
// mfma_f32_16x16x16_bf16(V_frag, P_frag) with P straight from registers.
// V_frag = b64 LDS read of V^T[d=l15][4 consec keys]. Removes both mid-loop
// lgkm waits (the R9 serialization). K/V double-buffered (64KB, merge
// scratch aliases post-loop) -> 1 barrier/tile. l-divide needs no shfl
// (all acc lanes share q=l15).

typedef __bf16 bf16;
typedef __attribute__((ext_vector_type(8))) __bf16 bf16x8;
typedef __attribute__((ext_vector_type(4))) __bf16 bf16x4;
typedef __attribute__((ext_vector_type(4))) float f32x4;
typedef __attribute__((ext_vector_type(4))) short s16x4;

#define LOG2E 1.44269504088896340736f
// Swizzled elem offset of an 8-elem group in a [rows][64] bf16 LDS tile.
#define SW(row, grp) (((row) << 6) + ((((grp) ^ ((row) & 7))) << 3))

__device__ __forceinline__ f32x4 pv_mfma16(bf16x4 v, bf16x4 p, f32x4 c) {
#if __has_builtin(__builtin_amdgcn_mfma_f32_16x16x16bf16_1k)
  return __builtin_amdgcn_mfma_f32_16x16x16bf16_1k(
      __builtin_bit_cast(s16x4, v), __builtin_bit_cast(s16x4, p), c, 0, 0, 0);
#elif __has_builtin(__builtin_amdgcn_mfma_f32_16x16x16_bf16)
  return __builtin_amdgcn_mfma_f32_16x16x16_bf16(v, p, c, 0, 0, 0);
#else
  f32x4 d;
  asm("v_mfma_f32_16x16x16_bf16 %0, %1, %2, %3"
      : "=v"(d) : "v"(v), "v"(p), "v"(c));
  return d;
#endif
}

// ---------------------------------------------------------------- LayerNorm
__global__ __launch_bounds__(256) void ln_kernel(
    const float* __restrict__ x, const float* __restrict__ gamma,
    const float* __restrict__ beta, bf16* __restrict__ h) {
  int wave = threadIdx.x >> 6, lane = threadIdx.x & 63;
  int row = blockIdx.x * 4 + wave;                 // 8192 rows
  const float* xr = x + (size_t)row * 512 + lane * 8;
  f32x4 v0 = *(const f32x4*)xr;
  f32x4 v1 = *(const f32x4*)(xr + 4);
  float f[8], s = 0.f, s2 = 0.f;
#pragma unroll
  for (int i = 0; i < 4; ++i) { f[i] = v0[i]; f[4 + i] = v1[i]; }
#pragma unroll
  for (int i = 0; i < 8; ++i) { s += f[i]; s2 += f[i] * f[i]; }
#pragma unroll
  for (int off = 1; off < 64; off <<= 1) {
    s  += __shfl_xor(s, off, 64);
    s2 += __shfl_xor(s2, off, 64);
  }
  float mu  = s * (1.f / 512.f);
  float var = s2 * (1.f / 512.f) - mu * mu;
  float rstd = rsqrtf(var + 1e-5f);
  f32x4 g0 = *(const f32x4*)(gamma + lane * 8);
  f32x4 g1 = *(const f32x4*)(gamma + lane * 8 + 4);
  f32x4 b0 = *(const f32x4*)(beta + lane * 8);
  f32x4 b1 = *(const f32x4*)(beta + lane * 8 + 4);
  bf16x8 o;
#pragma unroll
  for (int i = 0; i < 4; ++i) {
    o[i]     = (bf16)((f[i]     - mu) * rstd * g0[i] + b0[i]);
    o[4 + i] = (bf16)((f[4 + i] - mu) * rstd * g1[i] + b1[i]);
  }
  *(bf16x8*)(h + (size_t)row * 512 + lane * 8) = o;
}

// ------------------------------------------------------------- QKV GEMM
__global__ __launch_bounds__(256) void qkv_kernel(
    const bf16* __restrict__ h, const float* __restrict__ wq,
    const float* __restrict__ wk, const float* __restrict__ wv,
    bf16* __restrict__ Qg, bf16* __restrict__ Kg, bf16* __restrict__ Vtg) {
  __shared__ bf16 As[128 * 64];
  __shared__ bf16 Bs[128 * 64];
  int tid = threadIdx.x, wave = tid >> 6, lane = tid & 63;
  int wm = wave >> 1, wn = wave & 1, quad = lane >> 4, l15 = lane & 15;
  int mtile = blockIdx.x;          // 0..63
  int wsel = blockIdx.y >> 2;      // 0=q 1=k 2=v
  int nb = blockIdx.y & 3;
  const float* W = (wsel == 0) ? wq : (wsel == 1 ? wk : wv);
  const bf16*  Abase = h + (size_t)mtile * 128 * 512;
  const float* Bbase = W + (size_t)nb * 128 * 512;
  f32x4 acc[4][4];
#pragma unroll
  for (int i = 0; i < 4; ++i)
#pragma unroll
    for (int j = 0; j < 4; ++j) acc[i][j] = (f32x4){0.f, 0.f, 0.f, 0.f};

  int srow = tid >> 3, grp = tid & 7, scol = grp * 8;
  bf16x8 ar[4];
  f32x4 br0[4], br1[4];
#pragma unroll
  for (int k = 0; k < 4; ++k) {                 // prologue: tile 0 loads
    int rr = srow + k * 32;
    ar[k]  = *(const bf16x8*)(Abase + (size_t)rr * 512 + scol);
    br0[k] = *(const f32x4*)(Bbase + (size_t)rr * 512 + scol);
    br1[k] = *(const f32x4*)(Bbase + (size_t)rr * 512 + scol + 4);
  }
  for (int k0 = 0; k0 < 512; k0 += 64) {
#pragma unroll
    for (int k = 0; k < 4; ++k) {               // regs -> LDS
      int rr = srow + k * 32;
      int w = SW(rr, grp);
      *(bf16x8*)(As + w) = ar[k];
      bf16x8 wb;
#pragma unroll
      for (int j = 0; j < 4; ++j) { wb[j] = (bf16)br0[k][j]; wb[4 + j] = (bf16)br1[k][j]; }
      *(bf16x8*)(Bs + w) = wb;
    }
    __syncthreads();
    if (k0 < 448) {                             // prefetch next tile
#pragma unroll
      for (int k = 0; k < 4; ++k) {
        int rr = srow + k * 32;
        ar[k]  = *(const bf16x8*)(Abase + (size_t)rr * 512 + k0 + 64 + scol);
        br0[k] = *(const f32x4*)(Bbase + (size_t)rr * 512 + k0 + 64 + scol);
        br1[k] = *(const f32x4*)(Bbase + (size_t)rr * 512 + k0 + 64 + scol + 4);
      }
    }
#pragma unroll
    for (int c = 0; c < 2; ++c) {
      bf16x8 af[4], bw[4];
#pragma unroll
      for (int mt = 0; mt < 4; ++mt)
        af[mt] = *(const bf16x8*)(As + SW(wm * 64 + mt * 16 + l15, c * 4 + quad));
#pragma unroll
      for (int nt = 0; nt < 4; ++nt)
        bw[nt] = *(const bf16x8*)(Bs + SW(wn * 64 + nt * 16 + l15, c * 4 + quad));
#pragma unroll
      for (int mt = 0; mt < 4; ++mt)
#pragma unroll
        for (int nt = 0; nt < 4; ++nt)
          acc[mt][nt] = __builtin_amdgcn_mfma_f32_16x16x32_bf16(
              bw[nt], af[mt], acc[mt][nt], 0, 0, 0);
    }
    __syncthreads();
  }
  // Q pre-scale folds softmax 1/sqrt(64) AND log2(e) for exp2-based softmax.
  float qscale = (wsel == 0) ? (0.125f * LOG2E) : 1.0f;
#pragma unroll
  for (int mt = 0; mt < 4; ++mt) {
    int m_g = mtile * 128 + wm * 64 + mt * 16 + l15;   // token
    int b = m_g >> 12, s = m_g & 4095;
#pragma unroll
    for (int nt = 0; nt < 4; ++nt) {
      int n_g = nb * 128 + wn * 64 + nt * 16 + quad * 4;  // feature
      int head = n_g >> 6, d = n_g & 63;
      f32x4 a = acc[mt][nt];
      if (wsel < 2) {
        bf16* dst = (wsel == 0 ? Qg : Kg) +
                    ((size_t)((b * 8 + head) * 4096 + s)) * 64 + d;
        bf16x4 pk;
#pragma unroll
        for (int r = 0; r < 4; ++r) pk[r] = (bf16)(a[r] * qscale);
        *(bf16x4*)dst = pk;
      } else {
        bf16* dst = Vtg + ((size_t)((b * 8 + head) * 64 + d)) * 4096 + s;
#pragma unroll
        for (int r = 0; r < 4; ++r) dst[(size_t)r * 4096] = (bf16)a[r];
      }
    }
  }
}

// --------------------------------------------------------- Flash attention
// Block: 4 waves = (qgrp 0/1) x (khalf 0/1). 64 q/wave, keys
// [khalf*2048,+2048) in 32 tiles of 64. K/V double-buffered, 1 barrier/tile.
// o_acc layout: D[d=nt*16+quad*4+r][q=l15] (transposed vs R9).
__global__ __launch_bounds__(256, 2) void attn_kernel(
    const bf16* __restrict__ Qg, const bf16* __restrict__ Kg,
    const bf16* __restrict__ Vtg, bf16* __restrict__ Og) {
  __shared__ char smem[64 * 1024];
  bf16* KV = (bf16*)smem;               // [buf][khalf][K 4096 | V 4096]
  float* OL = (float*)smem;             // merge (post-loop alias): 2x4096 f32
  float* Ll = (float*)(smem + 49152);   // merge l: 128 f32 (post-loop alias)

  int tid = threadIdx.x, wave = tid >> 6, lane = tid & 63;
  int quad = lane >> 4, l15 = lane & 15;
  int qgrp = wave & 1, khalf = wave >> 1;
  int q0 = blockIdx.x * 128;
  int bh = blockIdx.y;
  int hi = bh & 7, bi = bh >> 3;
  const bf16* Kh  = Kg  + (size_t)bh * 4096 * 64;
  const bf16* Vth = Vtg + (size_t)bh * 64 * 4096;

  bf16x8 qf[4][2];   // Q pre-scaled by 0.125*LOG2E in qkv
#pragma unroll
  for (int mt = 0; mt < 4; ++mt)
#pragma unroll
    for (int c = 0; c < 2; ++c)
      qf[mt][c] = *(const bf16x8*)(
          Qg + ((size_t)bh * 4096 + q0 + qgrp * 64 + mt * 16 + l15) * 64 +
          c * 32 + quad * 8);

  f32x4 o_acc[4][4];
  float l_part[4] = {0.f, 0.f, 0.f, 0.f};
#pragma unroll
  for (int mt = 0; mt < 4; ++mt)
#pragma unroll
    for (int nt = 0; nt < 4; ++nt) o_acc[mt][nt] = (f32x4){0.f, 0.f, 0.f, 0.f};

  // Staging: wave (qgrp,khalf) stages stream qgrp (0=K,1=V) of its khalf.
  bf16* sbase = KV + khalf * 8192 + (qgrp ? 4096 : 0);
  bf16x8 sr[8];
  int key0 = khalf * 2048;
#pragma unroll
  for (int i = 0; i < 8; ++i) {          // tile 0
    int e = i * 512 + lane * 8;
    sr[i] = qgrp
        ? *(const bf16x8*)(Vth + (size_t)(e >> 6) * 4096 + key0 + (e & 63))
        : *(const bf16x8*)(Kh + (size_t)key0 * 64 + e);
  }
#pragma unroll
  for (int i = 0; i < 8; ++i) {          // write tile 0 -> buf0
    int e = i * 512 + lane * 8;
    *(bf16x8*)(sbase + SW(e >> 6, (e >> 3) & 7)) = sr[i];
  }
#pragma unroll
  for (int i = 0; i < 8; ++i) {          // prefetch tile 1
    int e = i * 512 + lane * 8;
    sr[i] = qgrp
        ? *(const bf16x8*)(Vth + (size_t)(e >> 6) * 4096 + key0 + 64 + (e & 63))
        : *(const bf16x8*)(Kh + (size_t)(key0 + 64) * 64 + e);
  }
  __syncthreads();

  for (int kt = 0; kt < 32; ++kt) {
    int cur = kt & 1, nxt = cur ^ 1;
    bf16* Ksw = KV + cur * 16384 + khalf * 8192;
    bf16* Vsw = Ksw + 4096;
    if (kt < 31) {                       // stage tile kt+1 -> other buffer
#pragma unroll
      for (int i = 0; i < 8; ++i) {
        int e = i * 512 + lane * 8;
        *(bf16x8*)(sbase + nxt * 16384 + SW(e >> 6, (e >> 3) & 7)) = sr[i];
      }
    }
    if (kt < 30) {                       // prefetch tile kt+2
      int kbase = key0 + (kt + 2) * 64;
#pragma unroll
      for (int i = 0; i < 8; ++i) {
        int e = i * 512 + lane * 8;
        sr[i] = qgrp
            ? *(const bf16x8*)(Vth + (size_t)(e >> 6) * 4096 + kbase + (e & 63))
            : *(const bf16x8*)(Kh + (size_t)kbase * 64 + e);
      }
    }
    // K fragments (b128) + V fragments (b64, for K=16 PV)
    bf16x8 kf[8];
#pragma unroll
    for (int kb = 0; kb < 4; ++kb)
#pragma unroll
      for (int c = 0; c < 2; ++c)
        kf[kb * 2 + c] = *(const bf16x8*)(Ksw + SW(kb * 16 + l15, c * 4 + quad));
    bf16x4 vf[16];
#pragma unroll
    for (int kb = 0; kb < 4; ++kb)
#pragma unroll
      for (int nt = 0; nt < 4; ++nt)
        vf[kb * 4 + nt] = *(const bf16x4*)(
            &Vsw[SW(nt * 16 + l15, kb * 2 + (quad >> 1)) + (quad & 1) * 4]);
    // per q-chunk: QK^T (S^T in regs) -> exp2 -> PV straight from registers
#pragma unroll
    for (int mt = 0; mt < 4; ++mt) {
      f32x4 st[4];
#pragma unroll
      for (int kb = 0; kb < 4; ++kb) st[kb] = (f32x4){0.f, 0.f, 0.f, 0.f};
#pragma unroll
      for (int c = 0; c < 2; ++c)
#pragma unroll
        for (int kb = 0; kb < 4; ++kb)
          st[kb] = __builtin_amdgcn_mfma_f32_16x16x32_bf16(
              kf[kb * 2 + c], qf[mt][c], st[kb], 0, 0, 0);
#pragma unroll
      for (int kb = 0; kb < 4; ++kb) {
        bf16x4 pk;
#pragma unroll
        for (int r = 0; r < 4; ++r) {
          float pv = __builtin_amdgcn_exp2f(st[kb][r]);
          l_part[mt] += pv;
          pk[r] = (bf16)pv;
        }
#pragma unroll
        for (int nt = 0; nt < 4; ++nt)
          o_acc[mt][nt] = pv_mfma16(vf[kb * 4 + nt], pk, o_acc[mt][nt]);
      }
    }
    __syncthreads();
  }
  // ---- merge the two key-halves (pure addition; no-max softmax) ----
#pragma unroll
  for (int mt = 0; mt < 4; ++mt) {       // all lanes get l for q=mt*16+l15
    l_part[mt] += __shfl_xor(l_part[mt], 16, 64);
    l_part[mt] += __shfl_xor(l_part[mt], 32, 64);
  }
  if (khalf == 1) {
    float* dst = OL + qgrp * 4096;
#pragma unroll
    for (int mt = 0; mt < 4; ++mt) {
#pragma unroll
      for (int nt = 0; nt < 4; ++nt) {
        int row = mt * 16 + l15;
        int g = nt * 4 + quad;
        int gs = (g & 8) | ((g ^ row) & 7);
        *(f32x4*)(&dst[row * 64 + gs * 4]) = o_acc[mt][nt];
      }
      if (quad == 0) Ll[qgrp * 64 + mt * 16 + l15] = l_part[mt];
    }
  }
  __syncthreads();
  if (khalf == 0) {
    const float* src = OL + qgrp * 4096;
#pragma unroll
    for (int mt = 0; mt < 4; ++mt) {
      float lt = l_part[mt] + Ll[qgrp * 64 + mt * 16 + l15];
      float inv = 1.0f / lt;
      int q = q0 + qgrp * 64 + mt * 16 + l15;
#pragma unroll
      for (int nt = 0; nt < 4; ++nt) {
        int row = mt * 16 + l15;
        int g = nt * 4 + quad;
        int gs = (g & 8) | ((g ^ row) & 7);
        f32x4 o = *(const f32x4*)(&src[row * 64 + gs * 4]);
        bf16x4 pk;
#pragma unroll
        for (int r = 0; r < 4; ++r)
          pk[r] = (bf16)((o[r] + o_acc[mt][nt][r]) * inv);
        *(bf16x4*)(&Og[((size_t)bi * 4096 + q) * 512 + hi * 64 + nt * 16 +
                       quad * 4]) = pk;
      }
    }
  }
}

// ----------------------------------------------- out = A @ Wo^T + bo + x
__global__ __launch_bounds__(256) void proj_kernel(
    const bf16* __restrict__ A, const float* __restrict__ Wo,
    const float* __restrict__ bo, const float* __restrict__ x,
    float* __restrict__ out) {
  __shared__ bf16 As[128 * 64];
  __shared__ bf16 Bs[128 * 64];
  int tid = threadIdx.x, wave = tid >> 6, lane = tid & 63;
  int wm = wave >> 1, wn = wave & 1, quad = lane >> 4, l15 = lane & 15;
  int mtile = blockIdx.x, nb = blockIdx.y;
  const bf16*  Abase = A + (size_t)mtile * 128 * 512;
  const float* Bbase = Wo + (size_t)nb * 128 * 512;
  f32x4 acc[4][4];
#pragma unroll
  for (int i = 0; i < 4; ++i)
#pragma unroll
    for (int j = 0; j < 4; ++j) acc[i][j] = (f32x4){0.f, 0.f, 0.f, 0.f};

  int srow = tid >> 3, grp = tid & 7, scol = grp * 8;
  bf16x8 ar[4];
  f32x4 br0[4], br1[4];
#pragma unroll
  for (int k = 0; k < 4; ++k) {
    int rr = srow + k * 32;
    ar[k]  = *(const bf16x8*)(Abase + (size_t)rr * 512 + scol);
    br0[k] = *(const f32x4*)(Bbase + (size_t)rr * 512 + scol);
    br1[k] = *(const f32x4*)(Bbase + (size_t)rr * 512 + scol + 4);
  }
  for (int k0 = 0; k0 < 512; k0 += 64) {
#pragma unroll
    for (int k = 0; k < 4; ++k) {
      int rr = srow + k * 32;
      int w = SW(rr, grp);
      *(bf16x8*)(As + w) = ar[k];
      bf16x8 wb;
#pragma unroll
      for (int j = 0; j < 4; ++j) { wb[j] = (bf16)br0[k][j]; wb[4 + j] = (bf16)br1[k][j]; }
      *(bf16x8*)(Bs + w) = wb;
    }
    __syncthreads();
    if (k0 < 448) {
#pragma unroll
      for (int k = 0; k < 4; ++k) {
        int rr = srow + k * 32;
        ar[k]  = *(const bf16x8*)(Abase + (size_t)rr * 512 + k0 + 64 + scol);
        br0[k] = *(const f32x4*)(Bbase + (size_t)rr * 512 + k0 + 64 + scol);
        br1[k] = *(const f32x4*)(Bbase + (size_t)rr * 512 + k0 + 64 + scol + 4);
      }
    }
#pragma unroll
    for (int c = 0; c < 2; ++c) {
      bf16x8 af[4], bw[4];
#pragma unroll
      for (int mt = 0; mt < 4; ++mt)
        af[mt] = *(const bf16x8*)(As + SW(wm * 64 + mt * 16 + l15, c * 4 + quad));
#pragma unroll
      for (int nt = 0; nt < 4; ++nt)
        bw[nt] = *(const bf16x8*)(Bs + SW(wn * 64 + nt * 16 + l15, c * 4 + quad));
#pragma unroll
      for (int mt = 0; mt < 4; ++mt)
#pragma unroll
        for (int nt = 0; nt < 4; ++nt)
          acc[mt][nt] = __builtin_amdgcn_mfma_f32_16x16x32_bf16(
              bw[nt], af[mt], acc[mt][nt], 0, 0, 0);
    }
    __syncthreads();
  }
#pragma unroll
  for (int mt = 0; mt < 4; ++mt) {
    int m_g = mtile * 128 + wm * 64 + mt * 16 + l15;
#pragma unroll
    for (int nt = 0; nt < 4; ++nt) {
      int n_g = nb * 128 + wn * 64 + nt * 16 + quad * 4;
      f32x4 a = acc[mt][nt];
      f32x4 xr = *(const f32x4*)(x + (size_t)m_g * 512 + n_g);
      f32x4 bb = *(const f32x4*)(bo + n_g);
      f32x4 o;
#pragma unroll
      for (int r = 0; r < 4; ++r)
        o[r] = a[r] + bb[r] + xr[r];
      *(f32x4*)(out + (size_t)m_g * 512 + n_g) = o;
    }
  }
}

extern "C" void kernel_launch(void* const* d_in, const int* in_sizes, int n_in,
                              void* d_out, int out_size, void* d_ws, size_t ws_size,
                              hipStream_t stream) {
  const float* x     = (const float*)d_in[0];
  const float* wq    = (const float*)d_in[1];
  const float* wk    = (const float*)d_in[2];
  const float* wv    = (const float*)d_in[3];
  const float* wo    = (const float*)d_in[4];
  const float* bo    = (const float*)d_in[5];
  const float* gamma = (const float*)d_in[6];
  const float* beta  = (const float*)d_in[7];
  float* out = (float*)d_out;
  char* ws = (char*)d_ws;
  const size_t SZ = (size_t)8192 * 512 * sizeof(bf16);  // 8 MB
  bf16* h   = (bf16*)(ws);          // aliased with Ao (h dead before attn)
  bf16* Ao  = (bf16*)(ws);
  bf16* Qg  = (bf16*)(ws + SZ);
  bf16* Kg  = (bf16*)(ws + 2 * SZ);
  bf16* Vtg = (bf16*)(ws + 3 * SZ);

  ln_kernel<<<2048, 256, 0, stream>>>(x, gamma, beta, h);
  qkv_kernel<<<dim3(64, 12), 256, 0, stream>>>(h, wq, wk, wv, Qg, Kg, Vtg);
  attn_kernel<<<dim3(32, 16), 256, 0, stream>>>(Qg, Kg, Vtg, Ao);
  proj_kernel<<<dim3(64, 4), 256, 0, stream>>>(Ao, wo, bo, x, out);
}

// Round 11
// 190.988 us; speedup vs baseline: 1.8140x; 1.0996x over previous
//
#include <hip/hip_runtime.h>
#include <hip/hip_bf16.h>
#include <stdint.h>

// B=2, S=4096, D=512, H=8, dk=64. fp32 in/out, bf16 MFMA internals.
// R11 (attn, on R10 skeleton — R10 is issue-bound at 87% combined pipes):
//  - PV as K=32 MFMA: P from kb-pair packs into one bf16x8 B-operand
//    (k-slot permutation legal since the V A-operand permutes identically)
//    -> 64 -> 32 PV MFMAs.
//  - l via ones-row MFMA (A=1s): l[q=l15] lands in every lane; kills 64
//    VALU adds + the end shuffles.
//  - packed bf16 cvt via v_perm (RTZ, hi-16 truncation): 1 instr / 2 scores.
//  - XCD-aware 1D grid swizzle (bid&7 -> bh pair) to stop K/V HBM re-fetch.

typedef __bf16 bf16;
typedef __attribute__((ext_vector_type(8))) __bf16 bf16x8;
typedef __attribute__((ext_vector_type(4))) __bf16 bf16x4;
typedef __attribute__((ext_vector_type(4))) float f32x4;
typedef __attribute__((ext_vector_type(4))) unsigned int u32x4;

#define LOG2E 1.44269504088896340736f
// Swizzled elem offset of an 8-elem group in a [rows][64] bf16 LDS tile.
#define SW(row, grp) (((row) << 6) + ((((grp) ^ ((row) & 7))) << 3))

// pack two f32 into (bf16(hi)<<16)|bf16(lo) by hi-16 truncation (RTZ)
__device__ __forceinline__ unsigned int pkbf16(float lo, float hi) {
  return __builtin_amdgcn_perm(__builtin_bit_cast(unsigned int, hi),
                               __builtin_bit_cast(unsigned int, lo),
                               0x07060302u);
}

// ---------------------------------------------------------------- LayerNorm
__global__ __launch_bounds__(256) void ln_kernel(
    const float* __restrict__ x, const float* __restrict__ gamma,
    const float* __restrict__ beta, bf16* __restrict__ h) {
  int wave = threadIdx.x >> 6, lane = threadIdx.x & 63;
  int row = blockIdx.x * 4 + wave;                 // 8192 rows
  const float* xr = x + (size_t)row * 512 + lane * 8;
  f32x4 v0 = *(const f32x4*)xr;
  f32x4 v1 = *(const f32x4*)(xr + 4);
  float f[8], s = 0.f, s2 = 0.f;
#pragma unroll
  for (int i = 0; i < 4; ++i) { f[i] = v0[i]; f[4 + i] = v1[i]; }
#pragma unroll
  for (int i = 0; i < 8; ++i) { s += f[i]; s2 += f[i] * f[i]; }
#pragma unroll
  for (int off = 1; off < 64; off <<= 1) {
    s  += __shfl_xor(s, off, 64);
    s2 += __shfl_xor(s2, off, 64);
  }
  float mu  = s * (1.f / 512.f);
  float var = s2 * (1.f / 512.f) - mu * mu;
  float rstd = rsqrtf(var + 1e-5f);
  f32x4 g0 = *(const f32x4*)(gamma + lane * 8);
  f32x4 g1 = *(const f32x4*)(gamma + lane * 8 + 4);
  f32x4 b0 = *(const f32x4*)(beta + lane * 8);
  f32x4 b1 = *(const f32x4*)(beta + lane * 8 + 4);
  bf16x8 o;
#pragma unroll
  for (int i = 0; i < 4; ++i) {
    o[i]     = (bf16)((f[i]     - mu) * rstd * g0[i] + b0[i]);
    o[4 + i] = (bf16)((f[4 + i] - mu) * rstd * g1[i] + b1[i]);
  }
  *(bf16x8*)(h + (size_t)row * 512 + lane * 8) = o;
}

// ------------------------------------------------------------- QKV GEMM
__global__ __launch_bounds__(256) void qkv_kernel(
    const bf16* __restrict__ h, const float* __restrict__ wq,
    const float* __restrict__ wk, const float* __restrict__ wv,
    bf16* __restrict__ Qg, bf16* __restrict__ Kg, bf16* __restrict__ Vtg) {
  __shared__ bf16 As[128 * 64];
  __shared__ bf16 Bs[128 * 64];
  int tid = threadIdx.x, wave = tid >> 6, lane = tid & 63;
  int wm = wave >> 1, wn = wave & 1, quad = lane >> 4, l15 = lane & 15;
  int mtile = blockIdx.x;          // 0..63
  int wsel = blockIdx.y >> 2;      // 0=q 1=k 2=v
  int nb = blockIdx.y & 3;
  const float* W = (wsel == 0) ? wq : (wsel == 1 ? wk : wv);
  const bf16*  Abase = h + (size_t)mtile * 128 * 512;
  const float* Bbase = W + (size_t)nb * 128 * 512;
  f32x4 acc[4][4];
#pragma unroll
  for (int i = 0; i < 4; ++i)
#pragma unroll
    for (int j = 0; j < 4; ++j) acc[i][j] = (f32x4){0.f, 0.f, 0.f, 0.f};

  int srow = tid >> 3, grp = tid & 7, scol = grp * 8;
  bf16x8 ar[4];
  f32x4 br0[4], br1[4];
#pragma unroll
  for (int k = 0; k < 4; ++k) {                 // prologue: tile 0 loads
    int rr = srow + k * 32;
    ar[k]  = *(const bf16x8*)(Abase + (size_t)rr * 512 + scol);
    br0[k] = *(const f32x4*)(Bbase + (size_t)rr * 512 + scol);
    br1[k] = *(const f32x4*)(Bbase + (size_t)rr * 512 + scol + 4);
  }
  for (int k0 = 0; k0 < 512; k0 += 64) {
#pragma unroll
    for (int k = 0; k < 4; ++k) {               // regs -> LDS
      int rr = srow + k * 32;
      int w = SW(rr, grp);
      *(bf16x8*)(As + w) = ar[k];
      bf16x8 wb;
#pragma unroll
      for (int j = 0; j < 4; ++j) { wb[j] = (bf16)br0[k][j]; wb[4 + j] = (bf16)br1[k][j]; }
      *(bf16x8*)(Bs + w) = wb;
    }
    __syncthreads();
    if (k0 < 448) {                             // prefetch next tile
#pragma unroll
      for (int k = 0; k < 4; ++k) {
        int rr = srow + k * 32;
        ar[k]  = *(const bf16x8*)(Abase + (size_t)rr * 512 + k0 + 64 + scol);
        br0[k] = *(const f32x4*)(Bbase + (size_t)rr * 512 + k0 + 64 + scol);
        br1[k] = *(const f32x4*)(Bbase + (size_t)rr * 512 + k0 + 64 + scol + 4);
      }
    }
#pragma unroll
    for (int c = 0; c < 2; ++c) {
      bf16x8 af[4], bw[4];
#pragma unroll
      for (int mt = 0; mt < 4; ++mt)
        af[mt] = *(const bf16x8*)(As + SW(wm * 64 + mt * 16 + l15, c * 4 + quad));
#pragma unroll
      for (int nt = 0; nt < 4; ++nt)
        bw[nt] = *(const bf16x8*)(Bs + SW(wn * 64 + nt * 16 + l15, c * 4 + quad));
#pragma unroll
      for (int mt = 0; mt < 4; ++mt)
#pragma unroll
        for (int nt = 0; nt < 4; ++nt)
          acc[mt][nt] = __builtin_amdgcn_mfma_f32_16x16x32_bf16(
              bw[nt], af[mt], acc[mt][nt], 0, 0, 0);
    }
    __syncthreads();
  }
  // Q pre-scale folds softmax 1/sqrt(64) AND log2(e) for exp2-based softmax.
  float qscale = (wsel == 0) ? (0.125f * LOG2E) : 1.0f;
#pragma unroll
  for (int mt = 0; mt < 4; ++mt) {
    int m_g = mtile * 128 + wm * 64 + mt * 16 + l15;   // token
    int b = m_g >> 12, s = m_g & 4095;
#pragma unroll
    for (int nt = 0; nt < 4; ++nt) {
      int n_g = nb * 128 + wn * 64 + nt * 16 + quad * 4;  // feature
      int head = n_g >> 6, d = n_g & 63;
      f32x4 a = acc[mt][nt];
      if (wsel < 2) {
        bf16* dst = (wsel == 0 ? Qg : Kg) +
                    ((size_t)((b * 8 + head) * 4096 + s)) * 64 + d;
        bf16x4 pk;
#pragma unroll
        for (int r = 0; r < 4; ++r) pk[r] = (bf16)(a[r] * qscale);
        *(bf16x4*)dst = pk;
      } else {
        bf16* dst = Vtg + ((size_t)((b * 8 + head) * 64 + d)) * 4096 + s;
#pragma unroll
        for (int r = 0; r < 4; ++r) dst[(size_t)r * 4096] = (bf16)a[r];
      }
    }
  }
}

// --------------------------------------------------------- Flash attention
// Block: 4 waves = (qgrp 0/1) x (khalf 0/1). 64 q/wave, keys
// [khalf*2048,+2048) in 32 tiles of 64. K/V double-buffered, 1 barrier/tile.
// o_acc: D[d=nt*16+quad*4+r][q=l15]. l via ones-row MFMA -> lacc[mt][*].
__global__ __launch_bounds__(256, 2) void attn_kernel(
    const bf16* __restrict__ Qg, const bf16* __restrict__ Kg,
    const bf16* __restrict__ Vtg, bf16* __restrict__ Og) {
  __shared__ char smem[64 * 1024];
  bf16* KV = (bf16*)smem;               // [buf][khalf][K 4096 | V 4096]
  float* OL = (float*)smem;             // merge (post-loop alias): 2x4096 f32
  float* Ll = (float*)(smem + 49152);   // merge l: 128 f32 (post-loop alias)

  int tid = threadIdx.x, wave = tid >> 6, lane = tid & 63;
  int quad = lane >> 4, l15 = lane & 15;
  int qgrp = wave & 1, khalf = wave >> 1;
  // XCD swizzle: consecutive block ids round-robin XCDs (R8-verified);
  // XCD k serves bh pair {2k,2k+1} -> 4MB K/V working set per XCD L2.
  int lin = blockIdx.x;                 // 0..511
  int bh = ((lin & 7) << 1) | ((lin >> 3) & 1);
  int q0 = (lin >> 4) * 128;
  int hi = bh & 7, bi = bh >> 3;
  const bf16* Kh  = Kg  + (size_t)bh * 4096 * 64;
  const bf16* Vth = Vtg + (size_t)bh * 64 * 4096;

  bf16x8 qf[4][2];   // Q pre-scaled by 0.125*LOG2E in qkv
#pragma unroll
  for (int mt = 0; mt < 4; ++mt)
#pragma unroll
    for (int c = 0; c < 2; ++c)
      qf[mt][c] = *(const bf16x8*)(
          Qg + ((size_t)bh * 4096 + q0 + qgrp * 64 + mt * 16 + l15) * 64 +
          c * 32 + quad * 8);

  f32x4 o_acc[4][4], lacc[4];
#pragma unroll
  for (int mt = 0; mt < 4; ++mt) {
    lacc[mt] = (f32x4){0.f, 0.f, 0.f, 0.f};
#pragma unroll
    for (int nt = 0; nt < 4; ++nt) o_acc[mt][nt] = (f32x4){0.f, 0.f, 0.f, 0.f};
  }
  const u32x4 onesu = {0x3F803F80u, 0x3F803F80u, 0x3F803F80u, 0x3F803F80u};
  const bf16x8 ones8 = __builtin_bit_cast(bf16x8, onesu);

  // Staging: wave (qgrp,khalf) stages stream qgrp (0=K,1=V) of its khalf.
  bf16* sbase = KV + khalf * 8192 + (qgrp ? 4096 : 0);
  bf16x8 sr[8];
  int key0 = khalf * 2048;
#pragma unroll
  for (int i = 0; i < 8; ++i) {          // tile 0
    int e = i * 512 + lane * 8;
    sr[i] = qgrp
        ? *(const bf16x8*)(Vth + (size_t)(e >> 6) * 4096 + key0 + (e & 63))
        : *(const bf16x8*)(Kh + (size_t)key0 * 64 + e);
  }
#pragma unroll
  for (int i = 0; i < 8; ++i) {          // write tile 0 -> buf0
    int e = i * 512 + lane * 8;
    *(bf16x8*)(sbase + SW(e >> 6, (e >> 3) & 7)) = sr[i];
  }
#pragma unroll
  for (int i = 0; i < 8; ++i) {          // prefetch tile 1
    int e = i * 512 + lane * 8;
    sr[i] = qgrp
        ? *(const bf16x8*)(Vth + (size_t)(e >> 6) * 4096 + key0 + 64 + (e & 63))
        : *(const bf16x8*)(Kh + (size_t)(key0 + 64) * 64 + e);
  }
  __syncthreads();

  for (int kt = 0; kt < 32; ++kt) {
    int cur = kt & 1, nxt = cur ^ 1;
    bf16* Ksw = KV + cur * 16384 + khalf * 8192;
    bf16* Vsw = Ksw + 4096;
    if (kt < 31) {                       // stage tile kt+1 -> other buffer
#pragma unroll
      for (int i = 0; i < 8; ++i) {
        int e = i * 512 + lane * 8;
        *(bf16x8*)(sbase + nxt * 16384 + SW(e >> 6, (e >> 3) & 7)) = sr[i];
      }
    }
    if (kt < 30) {                       // prefetch tile kt+2
      int kbase = key0 + (kt + 2) * 64;
#pragma unroll
      for (int i = 0; i < 8; ++i) {
        int e = i * 512 + lane * 8;
        sr[i] = qgrp
            ? *(const bf16x8*)(Vth + (size_t)(e >> 6) * 4096 + kbase + (e & 63))
            : *(const bf16x8*)(Kh + (size_t)kbase * 64 + e);
      }
    }
    // K fragments (b128) + V kb-pair fragments (2 x b64 -> bf16x8)
    bf16x8 kf[8];
#pragma unroll
    for (int kb = 0; kb < 4; ++kb)
#pragma unroll
      for (int c = 0; c < 2; ++c)
        kf[kb * 2 + c] = *(const bf16x8*)(Ksw + SW(kb * 16 + l15, c * 4 + quad));
    bf16x8 vf8[2][4];
#pragma unroll
    for (int pr = 0; pr < 2; ++pr)
#pragma unroll
      for (int nt = 0; nt < 4; ++nt) {
        bf16x4 lo = *(const bf16x4*)(
            &Vsw[SW(nt * 16 + l15, (pr * 2) * 2 + (quad >> 1)) + (quad & 1) * 4]);
        bf16x4 hi4 = *(const bf16x4*)(
            &Vsw[SW(nt * 16 + l15, (pr * 2 + 1) * 2 + (quad >> 1)) + (quad & 1) * 4]);
        bf16x8 v;
#pragma unroll
        for (int j = 0; j < 4; ++j) { v[j] = lo[j]; v[4 + j] = hi4[j]; }
        vf8[pr][nt] = v;
      }
    // per q-chunk: QK^T (S^T in regs) -> exp2/perm-pack -> K=32 PV + l-MFMA
#pragma unroll
    for (int mt = 0; mt < 4; ++mt) {
      f32x4 st[4];
#pragma unroll
      for (int kb = 0; kb < 4; ++kb) st[kb] = (f32x4){0.f, 0.f, 0.f, 0.f};
#pragma unroll
      for (int c = 0; c < 2; ++c)
#pragma unroll
        for (int kb = 0; kb < 4; ++kb)
          st[kb] = __builtin_amdgcn_mfma_f32_16x16x32_bf16(
              kf[kb * 2 + c], qf[mt][c], st[kb], 0, 0, 0);
#pragma unroll
      for (int pr = 0; pr < 2; ++pr) {
        float ea[4], eb[4];
#pragma unroll
        for (int r = 0; r < 4; ++r) {
          ea[r] = __builtin_amdgcn_exp2f(st[pr * 2][r]);
          eb[r] = __builtin_amdgcn_exp2f(st[pr * 2 + 1][r]);
        }
        u32x4 pw = {pkbf16(ea[0], ea[1]), pkbf16(ea[2], ea[3]),
                    pkbf16(eb[0], eb[1]), pkbf16(eb[2], eb[3])};
        bf16x8 pk8 = __builtin_bit_cast(bf16x8, pw);
#pragma unroll
        for (int nt = 0; nt < 4; ++nt)
          o_acc[mt][nt] = __builtin_amdgcn_mfma_f32_16x16x32_bf16(
              vf8[pr][nt], pk8, o_acc[mt][nt], 0, 0, 0);
        lacc[mt] = __builtin_amdgcn_mfma_f32_16x16x32_bf16(
            ones8, pk8, lacc[mt], 0, 0, 0);
      }
    }
    __syncthreads();
  }
  // ---- merge the two key-halves (pure addition; no-max softmax) ----
  // lacc[mt][r]: every lane holds l[q = mt*16 + l15] (all rows equal).
  if (khalf == 1) {
    float* dst = OL + qgrp * 4096;
#pragma unroll
    for (int mt = 0; mt < 4; ++mt) {
#pragma unroll
      for (int nt = 0; nt < 4; ++nt) {
        int row = mt * 16 + l15;
        int g = nt * 4 + quad;
        int gs = (g & 8) | ((g ^ row) & 7);
        *(f32x4*)(&dst[row * 64 + gs * 4]) = o_acc[mt][nt];
      }
      if (quad == 0) Ll[qgrp * 64 + mt * 16 + l15] = lacc[mt][0];
    }
  }
  __syncthreads();
  if (khalf == 0) {
    const float* src = OL + qgrp * 4096;
#pragma unroll
    for (int mt = 0; mt < 4; ++mt) {
      float lt = lacc[mt][0] + Ll[qgrp * 64 + mt * 16 + l15];
      float inv = 1.0f / lt;
      int q = q0 + qgrp * 64 + mt * 16 + l15;
#pragma unroll
      for (int nt = 0; nt < 4; ++nt) {
        int row = mt * 16 + l15;
        int g = nt * 4 + quad;
        int gs = (g & 8) | ((g ^ row) & 7);
        f32x4 o = *(const f32x4*)(&src[row * 64 + gs * 4]);
        bf16x4 pk;
#pragma unroll
        for (int r = 0; r < 4; ++r)
          pk[r] = (bf16)((o[r] + o_acc[mt][nt][r]) * inv);
        *(bf16x4*)(&Og[((size_t)bi * 4096 + q) * 512 + hi * 64 + nt * 16 +
                       quad * 4]) = pk;
      }
    }
  }
}

// ----------------------------------------------- out = A @ Wo^T + bo + x
__global__ __launch_bounds__(256) void proj_kernel(
    const bf16* __restrict__ A, const float* __restrict__ Wo,
    const float* __restrict__ bo, const float* __restrict__ x,
    float* __restrict__ out) {
  __shared__ bf16 As[128 * 64];
  __shared__ bf16 Bs[128 * 64];
  int tid = threadIdx.x, wave = tid >> 6, lane = tid & 63;
  int wm = wave >> 1, wn = wave & 1, quad = lane >> 4, l15 = lane & 15;
  int mtile = blockIdx.x, nb = blockIdx.y;
  const bf16*  Abase = A + (size_t)mtile * 128 * 512;
  const float* Bbase = Wo + (size_t)nb * 128 * 512;
  f32x4 acc[4][4];
#pragma unroll
  for (int i = 0; i < 4; ++i)
#pragma unroll
    for (int j = 0; j < 4; ++j) acc[i][j] = (f32x4){0.f, 0.f, 0.f, 0.f};

  int srow = tid >> 3, grp = tid & 7, scol = grp * 8;
  bf16x8 ar[4];
  f32x4 br0[4], br1[4];
#pragma unroll
  for (int k = 0; k < 4; ++k) {
    int rr = srow + k * 32;
    ar[k]  = *(const bf16x8*)(Abase + (size_t)rr * 512 + scol);
    br0[k] = *(const f32x4*)(Bbase + (size_t)rr * 512 + scol);
    br1[k] = *(const f32x4*)(Bbase + (size_t)rr * 512 + scol + 4);
  }
  for (int k0 = 0; k0 < 512; k0 += 64) {
#pragma unroll
    for (int k = 0; k < 4; ++k) {
      int rr = srow + k * 32;
      int w = SW(rr, grp);
      *(bf16x8*)(As + w) = ar[k];
      bf16x8 wb;
#pragma unroll
      for (int j = 0; j < 4; ++j) { wb[j] = (bf16)br0[k][j]; wb[4 + j] = (bf16)br1[k][j]; }
      *(bf16x8*)(Bs + w) = wb;
    }
    __syncthreads();
    if (k0 < 448) {
#pragma unroll
      for (int k = 0; k < 4; ++k) {
        int rr = srow + k * 32;
        ar[k]  = *(const bf16x8*)(Abase + (size_t)rr * 512 + k0 + 64 + scol);
        br0[k] = *(const f32x4*)(Bbase + (size_t)rr * 512 + k0 + 64 + scol);
        br1[k] = *(const f32x4*)(Bbase + (size_t)rr * 512 + k0 + 64 + scol + 4);
      }
    }
#pragma unroll
    for (int c = 0; c < 2; ++c) {
      bf16x8 af[4], bw[4];
#pragma unroll
      for (int mt = 0; mt < 4; ++mt)
        af[mt] = *(const bf16x8*)(As + SW(wm * 64 + mt * 16 + l15, c * 4 + quad));
#pragma unroll
      for (int nt = 0; nt < 4; ++nt)
        bw[nt] = *(const bf16x8*)(Bs + SW(wn * 64 + nt * 16 + l15, c * 4 + quad));
#pragma unroll
      for (int mt = 0; mt < 4; ++mt)
#pragma unroll
        for (int nt = 0; nt < 4; ++nt)
          acc[mt][nt] = __builtin_amdgcn_mfma_f32_16x16x32_bf16(
              bw[nt], af[mt], acc[mt][nt], 0, 0, 0);
    }
    __syncthreads();
  }
#pragma unroll
  for (int mt = 0; mt < 4; ++mt) {
    int m_g = mtile * 128 + wm * 64 + mt * 16 + l15;
#pragma unroll
    for (int nt = 0; nt < 4; ++nt) {
      int n_g = nb * 128 + wn * 64 + nt * 16 + quad * 4;
      f32x4 a = acc[mt][nt];
      f32x4 xr = *(const f32x4*)(x + (size_t)m_g * 512 + n_g);
      f32x4 bb = *(const f32x4*)(bo + n_g);
      f32x4 o;
#pragma unroll
      for (int r = 0; r < 4; ++r)
        o[r] = a[r] + bb[r] + xr[r];
      *(f32x4*)(out + (size_t)m_g * 512 + n_g) = o;
    }
  }
}

extern "C" void kernel_launch(void* const* d_in, const int* in_sizes, int n_in,
                              void* d_out, int out_size, void* d_ws, size_t ws_size,
                              hipStream_t stream) {
  const float* x     = (const float*)d_in[0];
  const float* wq    = (const float*)d_in[1];
  const float* wk    = (const float*)d_in[2];
  const float* wv    = (const float*)d_in[3];
  const float* wo    = (const float*)d_in[4];
  const float* bo    = (const float*)d_in[5];
  const float* gamma = (const float*)d_in[6];
  const float* beta  = (const float*)d_in[7];
  float* out = (float*)d_out;
  char* ws = (char*)d_ws;
  const size_t SZ = (size_t)8192 * 512 * sizeof(bf16);  // 8 MB
  bf16* h   = (bf16*)(ws);          // aliased with Ao (h dead before attn)
  bf16* Ao  = (bf16*)(ws);
  bf16* Qg  = (bf16*)(ws + SZ);
  bf16* Kg  = (bf16*)(ws + 2 * SZ);
  bf16* Vtg = (bf16*)(ws + 3 * SZ);

  ln_kernel<<<2048, 256, 0, stream>>>(x, gamma, beta, h);
  qkv_kernel<<<dim3(64, 12), 256, 0, stream>>>(h, wq, wk, wv, Qg, Kg, Vtg);
  attn_kernel<<<512, 256, 0, stream>>>(Qg, Kg, Vtg, Ao);
  proj_kernel<<<dim3(64, 4), 256, 0, stream>>>(Ao, wo, bo, x, out);
}